// Round 8
// baseline (34533.551 us; speedup 1.0000x reference)
//
#include <hip/hip_runtime.h>

// GRUNet: 2-layer GRU (B=128, T=512, I=64, H=256) + ReLU + FC(256->2).
// Round 8: CU-LOCAL RECURRENCES, register-resident weights, slack-buffered
// h0 stream.
//   - 256 WGs x 1024 thr (16 waves, 4/SIMD), 1 WG/CU:
//       WG b < 128     : layer0 of batch row b
//       WG 128 + b     : layer1 of batch row b
//   - Each WG's weights live ENTIRELY in VGPRs (L0: 240/thread, L1: 384).
//     Thread = (unit j 0..255, k-quarter q 0..3). 2-level shfl_xor k-reduce.
//   - Own h state in LDS double-buffer -> tight loop is dot/reduce/finish/
//     __syncthreads. NO cross-CU traffic on the recurrence.
//   - h0 stream L0->L1: mantissa-tagged ring (3 slots, tag cycle 4; proven
//     round 7). L1 prefetches h0(t+1) at step START (latency hidden under
//     dot); L0 runs ahead, WAR-guarded by L1 progress flag (lead <= 2).
//   - Activation LDS layout [2][4][68] ([2][4][20] for x): q-chunks padded
//     so the 4 concurrent broadcast addresses hit disjoint bank sets.
//   - FC fused into L1 WG after the last step.

namespace {
constexpr int kB = 128, kT = 512, kI = 64, kH = 256;
constexpr int RING = 3;            // h0 ring slots
constexpr int FS = 16;             // progress-flag stride (64B)
constexpr int HL = 272;            // [4][68] floats, one parity
}

using ull = unsigned long long;
using u32 = unsigned;

__device__ __forceinline__ float sigf(float v) { return 1.0f / (1.0f + expf(-v)); }
__device__ __forceinline__ float dot4(const float4 a, const float4 b) {
  return a.x * b.x + a.y * b.y + a.z * b.z + a.w * b.w;
}
__device__ __forceinline__ float redq(float v) {   // sum over q (lane bits 0-1)
  v += __shfl_xor(v, 1);
  v += __shfl_xor(v, 2);
  return v;
}
#define F4(p) (*(const float4*)(p))
#define AL(p)    __hip_atomic_load((p), __ATOMIC_RELAXED, __HIP_MEMORY_SCOPE_AGENT)
#define AS(p, v) __hip_atomic_store((p), (v), __ATOMIC_RELAXED, __HIP_MEMORY_SCOPE_AGENT)

__global__ __launch_bounds__(1024) void gru_pair(
    const float* __restrict__ x,
    const float* __restrict__ wih0, const float* __restrict__ whh0,
    const float* __restrict__ bih0, const float* __restrict__ bhh0,
    const float* __restrict__ wih1, const float* __restrict__ whh1,
    const float* __restrict__ bih1, const float* __restrict__ bhh1,
    const float* __restrict__ fcw, const float* __restrict__ fcb,
    u32* __restrict__ ring,        // [RING][kB][kH] tagged h0 dwords
    u32* __restrict__ prog,        // [kB][FS] layer1 progress
    float* __restrict__ out)
{
  __shared__ float hA[2 * HL];     // L0: h0 state | L1: h1 state
  __shared__ float hB[2 * HL];     // L0: x stage ([2][4][20]) | L1: h0 stage

  const int bid = blockIdx.x, tid = threadIdx.x;
  const bool isL1 = bid >= kB;
  const int row = isL1 ? bid - kB : bid;
  const int j = tid >> 2, q = tid & 3;

  u32* progp = prog + (size_t)row * FS;

  // zero own-state LDS (both parities; parity0 = h(-1) = 0)
  for (int i = tid; i < 2 * HL; i += 1024) hA[i] = 0.f;

  if (!isL1) {
    // ================= LAYER 0 (row = bid) =================
    // weights: ih k-slice [16q,16q+16), hh k-slice [64q,64q+64), 3 gates
    float4 wi[3][4], wh[3][16];
    #pragma unroll
    for (int g = 0; g < 3; ++g) {
      const float* pI = wih0 + (size_t)(g * kH + j) * kI + q * 16;
      #pragma unroll
      for (int c = 0; c < 4; ++c) wi[g][c] = F4(pI + 4 * c);
      const float* pH = whh0 + (size_t)(g * kH + j) * kH + q * 64;
      #pragma unroll
      for (int c = 0; c < 16; ++c) wh[g][c] = F4(pH + 4 * c);
    }
    const float fb_r = bih0[j] + bhh0[j];
    const float fb_z = bih0[kH + j] + bhh0[kH + j];
    const float fn_i = bih0[2 * kH + j];
    const float fn_h = bhh0[2 * kH + j];

    const float* xr = x + (size_t)row * kT * kI;
    // stage x(0) into parity 0 ([4][20]: chunk q' covers k [16q',..))
    if (tid < 16) {
      const float4 v = F4(xr + 4 * tid);
      *(float4*)(hB + 0 * 80 + (tid >> 2) * 20 + (tid & 3) * 4) = v;
    }
    __syncthreads();

    for (int t = 0; t < kT; ++t) {
      const int p = t & 1;
      // prefetch x(t+1) (plain loads, L2/L3-resident)
      float4 xpf;
      const bool hasx = (tid < 16) && (t + 1 < kT);
      if (hasx) xpf = F4(xr + (size_t)(t + 1) * kI + 4 * tid);

      // dot: x part (4 chunks) + h part (16 chunks)
      float ar = 0.f, az = 0.f, ani = 0.f, anh = 0.f;
      const float* xl = hB + p * 80 + q * 20;
      const float* hl = hA + p * HL + q * 68;
      #pragma unroll
      for (int c = 0; c < 4; ++c) {
        const float4 a = F4(xl + 4 * c);
        ar  += dot4(a, wi[0][c]);
        az  += dot4(a, wi[1][c]);
        ani += dot4(a, wi[2][c]);
      }
      #pragma unroll
      for (int c = 0; c < 16; ++c) {
        const float4 a = F4(hl + 4 * c);
        ar  += dot4(a, wh[0][c]);
        az  += dot4(a, wh[1][c]);
        anh += dot4(a, wh[2][c]);
      }
      ar = redq(ar); az = redq(az); ani = redq(ani); anh = redq(anh);

      if (q == 0) {
        // WAR guard: slot t%3 last consumed by L1 at its step t-3
        if (t >= 3) {
          while ((int)AL(progp) < t - 2) __builtin_amdgcn_s_sleep(1);
        }
        const float rr = sigf(ar + fb_r);
        const float zz = sigf(az + fb_z);
        const float nn = tanhf(ani + fn_i + rr * (anh + fn_h));
        const float hp = hA[p * HL + (j >> 6) * 68 + (j & 63)];
        const float hv = (1.f - zz) * nn + zz * hp;
        hA[(p ^ 1) * HL + (j >> 6) * 68 + (j & 63)] = hv;
        const u32 bits = (__float_as_uint(hv) & ~3u) | (u32)((t + 1) & 3);
        AS(ring + (size_t)(t % RING) * kB * kH + (size_t)row * kH + j, bits);
      }
      if (hasx) {
        *(float4*)(hB + (p ^ 1) * 80 + (tid >> 2) * 20 + (tid & 3) * 4) = xpf;
      }
      __syncthreads();
    }
  } else {
    // ================= LAYER 1 (row = bid-128) =================
    float4 wi[3][16], wh[3][16];   // ih vs h0, hh vs h1; k-slice [64q,..)
    #pragma unroll
    for (int g = 0; g < 3; ++g) {
      const float* pI = wih1 + (size_t)(g * kH + j) * kH + q * 64;
      const float* pH = whh1 + (size_t)(g * kH + j) * kH + q * 64;
      #pragma unroll
      for (int c = 0; c < 16; ++c) { wi[g][c] = F4(pI + 4 * c); wh[g][c] = F4(pH + 4 * c); }
    }
    const float fb_r = bih1[j] + bhh1[j];
    const float fb_z = bih1[kH + j] + bhh1[kH + j];
    const float fn_i = bih1[2 * kH + j];
    const float fn_h = bhh1[2 * kH + j];

    // bootstrap: stage h0(0) (slot 0, tag 1) into hB parity 0
    if (tid < 64) {
      const ull* ab = (const ull*)(ring + (size_t)row * kH) + 2 * tid;
      ull p0, p1;
      for (;;) {
        p0 = AL(ab); p1 = AL(ab + 1);
        const u32 bad = ((u32)p0 ^ 1u) | ((u32)(p0 >> 32) ^ 1u) |
                        ((u32)p1 ^ 1u) | ((u32)(p1 >> 32) ^ 1u);
        if (!(bad & 3u)) break;
        __builtin_amdgcn_s_sleep(1);
      }
      const float4 v = { __uint_as_float((u32)p0), __uint_as_float((u32)(p0 >> 32)),
                         __uint_as_float((u32)p1), __uint_as_float((u32)(p1 >> 32)) };
      *(float4*)(hB + 0 * HL + (tid >> 4) * 68 + (tid & 15) * 4) = v;
    }
    __syncthreads();

    for (int t = 0; t < kT; ++t) {
      const int p = t & 1;
      if (tid == 0) AS(progp, (u32)(t + 1));   // staged h0(t) -> L0 may reuse slot t-3

      // issue prefetch of h0(t+1) NOW (latency hides under the dot)
      ull p0 = 0, p1 = 0;
      const ull* pfa = nullptr;
      const bool haspf = (tid < 64) && (t + 1 < kT);
      if (haspf) {
        pfa = (const ull*)(ring + (size_t)((t + 1) % RING) * kB * kH +
                           (size_t)row * kH) + 2 * tid;
        p0 = AL(pfa); p1 = AL(pfa + 1);
      }

      // dot: ih vs h0stage + hh vs h1state (16 chunks each)
      float ar = 0.f, az = 0.f, ani = 0.f, anh = 0.f;
      const float* h0s = hB + p * HL + q * 68;
      const float* h1l = hA + p * HL + q * 68;
      #pragma unroll
      for (int c = 0; c < 16; ++c) {
        const float4 a0 = F4(h0s + 4 * c);
        ar  += dot4(a0, wi[0][c]);
        az  += dot4(a0, wi[1][c]);
        ani += dot4(a0, wi[2][c]);
        const float4 a1 = F4(h1l + 4 * c);
        ar  += dot4(a1, wh[0][c]);
        az  += dot4(a1, wh[1][c]);
        anh += dot4(a1, wh[2][c]);
      }
      ar = redq(ar); az = redq(az); ani = redq(ani); anh = redq(anh);

      if (q == 0) {
        const float rr = sigf(ar + fb_r);
        const float zz = sigf(az + fb_z);
        const float nn = tanhf(ani + fn_i + rr * (anh + fn_h));
        const float hp = hA[p * HL + (j >> 6) * 68 + (j & 63)];
        hA[(p ^ 1) * HL + (j >> 6) * 68 + (j & 63)] = (1.f - zz) * nn + zz * hp;
      }

      // verify tags of h0(t+1), spin-reload if L0 not there yet; stage it
      if (haspf) {
        const u32 e = (u32)((t + 2) & 3);
        for (;;) {
          const u32 bad = ((u32)p0 ^ e) | ((u32)(p0 >> 32) ^ e) |
                          ((u32)p1 ^ e) | ((u32)(p1 >> 32) ^ e);
          if (!(bad & 3u)) break;
          __builtin_amdgcn_s_sleep(1);
          p0 = AL(pfa); p1 = AL(pfa + 1);
        }
        const float4 v = { __uint_as_float((u32)p0), __uint_as_float((u32)(p0 >> 32)),
                           __uint_as_float((u32)p1), __uint_as_float((u32)(p1 >> 32)) };
        *(float4*)(hB + (p ^ 1) * HL + (tid >> 4) * 68 + (tid & 15) * 4) = v;
      }
      __syncthreads();
    }

    // FC epilogue: h1(T-1) sits in hA parity 0 ((511&1)^1)
    if (tid < 64) {
      const int o = tid & 1, seg = tid >> 1;          // 32 segs x 8 k
      const float* wfc = fcw + (size_t)o * kH;
      float acc = 0.f;
      #pragma unroll
      for (int kk = 0; kk < 8; ++kk) {
        const int k = seg * 8 + kk;
        const float hv = hA[0 * HL + (k >> 6) * 68 + (k & 63)];
        acc += fmaxf(hv, 0.f) * wfc[k];
      }
      acc += __shfl_xor(acc, 2);
      acc += __shfl_xor(acc, 4);
      acc += __shfl_xor(acc, 8);
      acc += __shfl_xor(acc, 16);
      acc += __shfl_xor(acc, 32);
      if (tid < 2) out[row * 2 + tid] = acc + fcb[tid];
    }
  }
}

extern "C" void kernel_launch(void* const* d_in, const int* in_sizes, int n_in,
                              void* d_out, int out_size, void* d_ws, size_t ws_size,
                              hipStream_t stream) {
  const float* x    = (const float*)d_in[0];
  const float* wih0 = (const float*)d_in[1];
  const float* whh0 = (const float*)d_in[2];
  const float* bih0 = (const float*)d_in[3];
  const float* bhh0 = (const float*)d_in[4];
  const float* wih1 = (const float*)d_in[5];
  const float* whh1 = (const float*)d_in[6];
  const float* bih1 = (const float*)d_in[7];
  const float* bhh1 = (const float*)d_in[8];
  const float* fcw  = (const float*)d_in[9];
  const float* fcb  = (const float*)d_in[10];

  u32* ring = (u32*)d_ws;                              // [RING][kB][kH]
  u32* prog = ring + (size_t)RING * kB * kH;           // [kB][FS]
  float* out = (float*)d_out;

  // zero ring (tag 0 != any expected tag until written) + progress flags
  hipMemsetAsync(d_ws, 0,
                 ((size_t)RING * kB * kH + (size_t)kB * FS) * sizeof(u32),
                 stream);

  gru_pair<<<2 * kB, 1024, 0, stream>>>(
      x, wih0, whh0, bih0, bhh0, wih1, whh1, bih1, bhh1,
      fcw, fcb, ring, prog, out);
}

// Round 9
// 5725.788 us; speedup vs baseline: 6.0312x; 6.0312x over previous
//
#include <hip/hip_runtime.h>

// GRUNet: 2-layer GRU (B=128, T=512, I=64, H=256) + ReLU + FC(256->2).
// Round 9: r7 structure + SET ROTATION to hide MALL latency.
//   - 8 groups x 32 WGs x 512 thr; WG owns 8 units of both layers;
//     register-resident weight slices (96 VGPR/thread, r6/r7-proven).
//   - Group's 16 rows split into 4 SETS of 4 rows. Step s runs as 4 slots
//     (one per set). A set's consecutive steps are 4 slots apart -> its
//     produced h has ~3 slots (~1.5us) to propagate through MALL before
//     consumption: latency hidden by other sets' compute.
//   - Slot = {phaseA: publish sd, WAR guard, PREFETCH slot K+1 h (loads
//     fly under dot), dot set m, partials} sync {phaseB: finish set m
//     (64 thr) || tag-verify + LDS-stage set m+1} sync.
//   - Mantissa-tag dataflow (2 LSBs, ring 3, tag cycle 4) as r7.
//   - WAR guard: flat-slot counter sd; writer at flat K requires all
//     group WGs sd >= K-7 (staged K-8 done). Covers prologue (r7 had
//     an ABA window there).

namespace {
constexpr int kB = 128, kT = 512, kI = 64, kH = 256, kBH = kB * kH;
constexpr int RPG = 16, NWG = 256, NT = 512;

// activation stage: [kseg 8][row 16][32], row stride 36, kseg stride 580
constexpr int SRS = 36;
constexpr int SKS = 16 * SRS + 4;          // 580
constexpr int O_S0 = 0;
constexpr int O_S1 = O_S0 + 8 * SKS;
constexpr int O_X  = O_S1 + 8 * SKS;       // [16][68]
constexpr int O_PB = O_X + RPG * 68;       // partials [4][16][36]
constexpr int PBN  = 4 * 16 * 36;
constexpr int LDSF = O_PB + PBN;           // 12672 floats = 49.5 KB

constexpr int FS = 16;                     // sd flag stride (64B)
}

using ull = unsigned long long;
using u32 = unsigned;

__device__ __forceinline__ float sigf(float v) { return 1.0f / (1.0f + expf(-v)); }
__device__ __forceinline__ float dot4(const float4 a, const float4 b) {
  return a.x * b.x + a.y * b.y + a.z * b.z + a.w * b.w;
}
__device__ __forceinline__ float red8(float v) {   // sum over kseg lanes (bits 3..5)
  v += __shfl_xor(v, 8);
  v += __shfl_xor(v, 16);
  v += __shfl_xor(v, 32);
  return v;
}
#define F4(p) (*(const float4*)(p))
#define AL(p)    __hip_atomic_load((p), __ATOMIC_RELAXED, __HIP_MEMORY_SCOPE_AGENT)
#define AS(p, v) __hip_atomic_store((p), (v), __ATOMIC_RELAXED, __HIP_MEMORY_SCOPE_AGENT)

__global__ __launch_bounds__(NT, 2) void gru_persistent(
    const float* __restrict__ x,
    const float* __restrict__ wih0, const float* __restrict__ whh0,
    const float* __restrict__ bih0, const float* __restrict__ bhh0,
    const float* __restrict__ wih1, const float* __restrict__ whh1,
    const float* __restrict__ bih1, const float* __restrict__ bhh1,
    const float* __restrict__ fcw, const float* __restrict__ fcb,
    u32* __restrict__ h0w,    // [3][B][H] tagged dwords
    u32* __restrict__ h1w,    // [3][B][H] tagged dwords
    u32* __restrict__ sd,     // [NWG][FS] staged-slot counters
    float* __restrict__ out)
{
  __shared__ float lds[LDSF];

  const int bid = blockIdx.x;
  const int g   = bid >> 5;
  const int wg  = bid & 31;
  const int tid = threadIdx.x;
  const int r0  = g * RPG;
  const int j0  = wg * 8;

  const int wave = tid >> 6, lane = tid & 63;
  const int lay  = wave >> 2;          // 0,1
  const int fam  = (wave >> 1) & 1;
  const int rh   = wave & 1;
  const int ju   = lane & 7;
  const int ks   = lane >> 3;
  const int jg   = j0 + ju;

  for (int i = tid; i < PBN; i += NT) lds[O_PB + i] = 0.f;

  // ---- weight slices into registers (once) — r7 verbatim ----
  float4 wr0[8], wr1[8], wr2[8];
  if (lay == 0) {
    if (fam == 0) {
#define L0F0(wrg, gg) { \
      const float* wi = wih0 + (size_t)((gg) * kH + jg) * kI + ks * 8;   \
      const float* wh = whh0 + (size_t)((gg) * kH + jg) * kH + ks * 32;  \
      wrg[0] = F4(wi); wrg[1] = F4(wi + 4);                              \
      wrg[2] = F4(wh); wrg[3] = F4(wh + 4); wrg[4] = F4(wh + 8); }
      L0F0(wr0, 0) L0F0(wr1, 1) L0F0(wr2, 2)
    } else {
#define L0F1(wrg, gg) { \
      const float* wh = whh0 + (size_t)((gg) * kH + jg) * kH + ks * 32 + 12; \
      wrg[0] = F4(wh); wrg[1] = F4(wh + 4); wrg[2] = F4(wh + 8);             \
      wrg[3] = F4(wh + 12); wrg[4] = F4(wh + 16); }
      L0F1(wr0, 0) L0F1(wr1, 1) L0F1(wr2, 2)
    }
  } else {
    const float* ws = fam ? whh1 : wih1;
#define L1W(wrg, gg) { \
    const float* wp = ws + (size_t)((gg) * kH + jg) * kH + ks * 32;          \
    wrg[0] = F4(wp);      wrg[1] = F4(wp + 4);  wrg[2] = F4(wp + 8);         \
    wrg[3] = F4(wp + 12); wrg[4] = F4(wp + 16); wrg[5] = F4(wp + 20);        \
    wrg[6] = F4(wp + 24); wrg[7] = F4(wp + 28); }
    L1W(wr0, 0) L1W(wr1, 1) L1W(wr2, 2)
  }

  // ---- finisher constants (tid < 64: layf = tid>>5, uf = tid&7) ----
  float fb_r = 0.f, fb_z = 0.f, fn_i = 0.f, fn_h = 0.f;
  if (tid < 64) {
    const int layf = tid >> 5, uf = tid & 7, jf = j0 + uf;
    const float* bi = layf ? bih1 : bih0;
    const float* bh = layf ? bhh1 : bhh0;
    fb_r = bi[jf] + bh[jf];
    fb_z = bi[kH + jf] + bh[kH + jf];
    fn_i = bi[2 * kH + jf];
    fn_h = bh[2 * kH + jf];
  }

  u32* sdp = sd + (u32)bid * FS;
  const int sro = tid >> 7, sk2 = tid & 127;   // staged row-in-set, u64 col

  // ---- prologue: stage slot 0 = (s'=0, set 0): h0(-1) zeros (tag 0) ----
  {
    const ull* a0 = (const ull*)(h0w + (size_t)2 * kBH +        // (0+2)%3
                                 (size_t)(r0 + sro) * kH) + sk2;
    ull v0 = AL(a0);
    while ((((u32)v0 | (u32)(v0 >> 32)) & 3u)) {
      __builtin_amdgcn_s_sleep(1);
      v0 = AL(a0);
    }
    const int ksg = sk2 >> 4, off = (sk2 * 2) & 31;
    float2 f0; __builtin_memcpy(&f0, &v0, 8);
    *(float2*)(lds + O_S0 + ksg * SKS + sro * SRS + off) = f0;
    if (tid < 64) {
      const int rx = tid >> 4, c4 = (tid & 15) * 4;
      *(float4*)(lds + O_X + rx * 68 + c4) =
          F4(x + (size_t)(r0 + rx) * kT * kI + c4);
    }
  }
  __syncthreads();

  // ---- main loop: 513 steps x 4 slots ----
  for (int s = 0; s <= kT; ++s) {
    for (int m = 0; m < 4; ++m) {
      const int K  = s * 4 + m;
      const int m2 = (m + 1) & 3;
      const int s2 = (m == 3) ? s + 1 : s;
      const bool dostage = (s2 <= kT);

      // ======== phase A ========
      if (tid == 0) AS(sdp, (u32)(K + 1));     // staged(K) complete
      if (K >= 8 && tid >= 480) {              // writer guard: staged(K-8) everywhere
        const u32* f = sd + (u32)((g << 5) + (tid - 480)) * FS;
        while ((int)AL(f) < K - 7) __builtin_amdgcn_s_sleep(1);
      }

      // prefetch slot K+1 (loads fly under the dot)
      ull v0 = 0, v1 = 0; float4 xpf = {};
      const ull *a0 = nullptr, *a1 = nullptr;
      if (dostage) {
        const int ro2 = m2 * 4 + sro;
        a0 = (const ull*)(h0w + (size_t)((s2 + 2) % 3) * kBH +
                          (size_t)(r0 + ro2) * kH) + sk2;
        v0 = AL(a0);
        if (s2 >= 1) {
          a1 = (const ull*)(h1w + (size_t)((s2 + 1) % 3) * kBH +
                            (size_t)(r0 + ro2) * kH) + sk2;
          v1 = AL(a1);
        }
        if (tid < 64 && s2 < kT) {
          const int rx = m2 * 4 + (tid >> 4), c4 = (tid & 15) * 4;
          xpf = F4(x + (size_t)(r0 + rx) * kT * kI + (size_t)s2 * kI + c4);
        }
      }

      // dot for set m (2 rows per wave)
      const bool wact = lay ? (s >= 1) : (s < kT);
      if (wact) {
        float prr[2], pzz[2], pni[2], pnh[2];
        #pragma unroll
        for (int r = 0; r < 2; ++r) {
          const int ro = m * 4 + rh * 2 + r;
          float pr = 0.f, pz = 0.f, pxi = 0.f, pxh = 0.f;
          if (lay == 0) {
            if (fam == 0) {
              const float* ax = lds + O_X + ro * 68 + ks * 8;
              const float4 x0 = F4(ax), x1 = F4(ax + 4);
              pr  += dot4(x0, wr0[0]) + dot4(x1, wr0[1]);
              pz  += dot4(x0, wr1[0]) + dot4(x1, wr1[1]);
              pxi += dot4(x0, wr2[0]) + dot4(x1, wr2[1]);
              const float* ah = lds + O_S0 + ks * SKS + ro * SRS;
              #pragma unroll
              for (int i = 0; i < 3; ++i) {
                const float4 hv = F4(ah + i * 4);
                pr  += dot4(hv, wr0[2 + i]);
                pz  += dot4(hv, wr1[2 + i]);
                pxh += dot4(hv, wr2[2 + i]);
              }
            } else {
              const float* ah = lds + O_S0 + ks * SKS + ro * SRS + 12;
              #pragma unroll
              for (int i = 0; i < 5; ++i) {
                const float4 hv = F4(ah + i * 4);
                pr  += dot4(hv, wr0[i]);
                pz  += dot4(hv, wr1[i]);
                pxh += dot4(hv, wr2[i]);
              }
            }
          } else {
            const float* aa = lds + (fam ? O_S1 : O_S0) + ks * SKS + ro * SRS;
            #pragma unroll
            for (int i = 0; i < 8; ++i) {
              const float4 av = F4(aa + i * 4);
              pr += dot4(av, wr0[i]);
              pz += dot4(av, wr1[i]);
              if (fam) pxh += dot4(av, wr2[i]);
              else     pxi += dot4(av, wr2[i]);
            }
          }
          prr[r] = pr; pzz[r] = pz; pni[r] = pxi; pnh[r] = pxh;
        }
        #pragma unroll
        for (int r = 0; r < 2; ++r) { prr[r] = red8(prr[r]); pzz[r] = red8(pzz[r]); }
        if (lay == 0 && fam == 0) {
          #pragma unroll
          for (int r = 0; r < 2; ++r) { pni[r] = red8(pni[r]); pnh[r] = red8(pnh[r]); }
        } else if (fam == 0) {
          #pragma unroll
          for (int r = 0; r < 2; ++r) pni[r] = red8(pni[r]);
        } else {
          #pragma unroll
          for (int r = 0; r < 2; ++r) pnh[r] = red8(pnh[r]);
        }
        if (ks == 0) {
          #pragma unroll
          for (int r = 0; r < 2; ++r) {
            const int ro = m * 4 + rh * 2 + r;
            float* pb = lds + O_PB + ((wave >> 1) * 16 + ro) * SRS + ju;
            pb[0] = prr[r]; pb[8] = pzz[r];
            if (lay == 0 && fam == 0) { pb[16] = pni[r]; pb[24] = pnh[r]; }
            else if (fam == 0)          pb[16] = pni[r];
            else                        pb[24] = pnh[r];
          }
        }
      }
      __syncthreads();

      // ======== phase B ========
      // finish set m (64 threads) — concurrent with stage of set m2 (disjoint LDS rows)
      if (tid < 64) {
        const int layf = tid >> 5;
        const bool act = layf ? (s >= 1) : (s < kT);
        if (act) {
          const int local = tid & 31, rof = m * 4 + (local >> 3), uf = local & 7;
          const int jf = j0 + uf;
          const float* p0 = lds + O_PB + ((layf * 2) * 16 + rof) * SRS + uf;
          const float* p1 = p0 + 16 * SRS;
          const float rr = sigf(p0[0] + p1[0] + fb_r);
          const float zz = sigf(p0[8] + p1[8] + fb_z);
          const float nn = tanhf(p0[16] + p1[16] + fn_i +
                                 rr * (p0[24] + p1[24] + fn_h));
          const float hp = lds[(layf ? O_S1 : O_S0) +
                               (jf >> 5) * SKS + rof * SRS + (jf & 31)];
          const float hv = (1.f - zz) * nn + zz * hp;
          const int slot = layf ? ((s - 1) % 3) : (s % 3);
          const u32 tag = layf ? (u32)(s & 3) : (u32)((s + 1) & 3);
          const u32 bits = (__float_as_uint(hv) & ~3u) | tag;
          u32* hw = (layf ? h1w : h0w) + (size_t)slot * kBH +
                    (size_t)(r0 + rof) * kH + jf;
          AS(hw, bits);
        }
      }
      // stage set m2 for step s2: verify tags (retry rare), write LDS
      if (dostage) {
        const u32 e0 = (u32)(s2 & 3), e1 = (u32)((s2 - 1) & 3);
        for (;;) {
          u32 bad = ((u32)v0 ^ e0) | ((u32)(v0 >> 32) ^ e0);
          if (s2 >= 1) bad |= ((u32)v1 ^ e1) | ((u32)(v1 >> 32) ^ e1);
          if (!(bad & 3u)) break;
          __builtin_amdgcn_s_sleep(1);
          v0 = AL(a0);
          if (s2 >= 1) v1 = AL(a1);
        }
        const int ro2 = m2 * 4 + sro, ksg = sk2 >> 4, off = (sk2 * 2) & 31;
        float2 f0; __builtin_memcpy(&f0, &v0, 8);
        *(float2*)(lds + O_S0 + ksg * SKS + ro2 * SRS + off) = f0;
        if (s2 >= 1) {
          float2 f1; __builtin_memcpy(&f1, &v1, 8);
          *(float2*)(lds + O_S1 + ksg * SKS + ro2 * SRS + off) = f1;
        }
        if (tid < 64 && s2 < kT) {
          const int rx = m2 * 4 + (tid >> 4), c4 = (tid & 15) * 4;
          *(float4*)(lds + O_X + rx * 68 + c4) = xpf;
        }
      }
      __syncthreads();
    }
  }

  // ---- FC epilogue: group's WG0; h1(T-1) slot (kT-1)%3, tag kT&3 ----
  if (wg == 0 && tid < 256) {
    const int rv = tid >> 4, o = (tid >> 3) & 1, kseg = tid & 7;
    const u32* hf = h1w + (size_t)((kT - 1) % 3) * kBH + (size_t)(r0 + rv) * kH;
    const float* wfc = fcw + (size_t)o * kH;
    float acc = 0.f;
    for (int k = kseg * 32; k < kseg * 32 + 32; ++k) {
      u32 b;
      do {
        b = AL(hf + k);
      } while ((b & 3u) != (u32)(kT & 3));
      acc += fmaxf(__uint_as_float(b), 0.f) * wfc[k];
    }
    acc += __shfl_xor(acc, 1);
    acc += __shfl_xor(acc, 2);
    acc += __shfl_xor(acc, 4);
    if (kseg == 0) out[(r0 + rv) * 2 + o] = acc + fcb[o];
  }
}

extern "C" void kernel_launch(void* const* d_in, const int* in_sizes, int n_in,
                              void* d_out, int out_size, void* d_ws, size_t ws_size,
                              hipStream_t stream) {
  const float* x    = (const float*)d_in[0];
  const float* wih0 = (const float*)d_in[1];
  const float* whh0 = (const float*)d_in[2];
  const float* bih0 = (const float*)d_in[3];
  const float* bhh0 = (const float*)d_in[4];
  const float* wih1 = (const float*)d_in[5];
  const float* whh1 = (const float*)d_in[6];
  const float* bih1 = (const float*)d_in[7];
  const float* bhh1 = (const float*)d_in[8];
  const float* fcw  = (const float*)d_in[9];
  const float* fcb  = (const float*)d_in[10];

  u32* h0w = (u32*)d_ws;                 // [3][B][H] tagged
  u32* h1w = h0w + 3 * kBH;              // [3][B][H] tagged
  u32* sd  = h1w + 3 * kBH;              // [NWG][FS]
  float* out = (float*)d_out;

  // zero tagged h buffers (tag 0 == t=-1 state) + sd counters
  hipMemsetAsync(d_ws, 0,
                 (size_t)(6 * kBH) * sizeof(u32) +
                 (size_t)NWG * FS * sizeof(u32), stream);

  gru_persistent<<<NWG, NT, 0, stream>>>(
      x, wih0, whh0, bih0, bhh0, wih1, whh1, bih1, bhh1,
      fcw, fcb, h0w, h1w, sd, out);
}

// Round 10
// 4083.347 us; speedup vs baseline: 8.4572x; 1.4022x over previous
//
#include <hip/hip_runtime.h>

// GRUNet: 2-layer GRU (B=128, T=512, I=64, H=256) + ReLU + FC(256->2).
// Round 10: r7 structure minus redundant sync machinery.
//   - PROOF: in the all-to-all group, slot overwrite (step s+3) is
//     value-causally ordered (dense matvec) after every WG's read of
//     that slot (step s+1) -> sd WAR flags were redundant. DELETED.
//   - LDS stage+partials DOUBLE-BUFFERED -> 2 syncthreads/step (was 3).
//   - finish(s-1) at top of iteration s: sweep loads pre-issued before
//     it, retry overlaps the gate math (T14 issue-early pattern).
//   - Mantissa-tag dataflow (2 LSBs, ring 3, tag cycle 4) as r7.
//   - Register-resident weight slices, dot/reduce/partials: r7 verbatim.

namespace {
constexpr int kB = 128, kT = 512, kI = 64, kH = 256, kBH = kB * kH;
constexpr int RPG = 16, NWG = 256, NT = 512;

// activation stage: [kseg 8][row 16][32], row stride 36, kseg stride 580
constexpr int SRS = 36;
constexpr int SKS = 16 * SRS + 4;          // 580
constexpr int O_S0 = 0;
constexpr int O_S1 = O_S0 + 8 * SKS;
constexpr int O_X  = O_S1 + 8 * SKS;       // [16][68]
constexpr int O_PB = O_X + RPG * 68;       // partials [4][16][36]
constexpr int PBN  = 4 * 16 * 36;
constexpr int LDSF = O_PB + PBN;           // 12672 floats; x2 buffers = 99 KB
}

using ull = unsigned long long;
using u32 = unsigned;

__device__ __forceinline__ float sigf(float v) { return 1.0f / (1.0f + expf(-v)); }
__device__ __forceinline__ float dot4(const float4 a, const float4 b) {
  return a.x * b.x + a.y * b.y + a.z * b.z + a.w * b.w;
}
__device__ __forceinline__ float red8(float v) {   // sum over kseg lanes (bits 3..5)
  v += __shfl_xor(v, 8);
  v += __shfl_xor(v, 16);
  v += __shfl_xor(v, 32);
  return v;
}
#define F4(p) (*(const float4*)(p))
#define AL(p)    __hip_atomic_load((p), __ATOMIC_RELAXED, __HIP_MEMORY_SCOPE_AGENT)
#define AS(p, v) __hip_atomic_store((p), (v), __ATOMIC_RELAXED, __HIP_MEMORY_SCOPE_AGENT)

__global__ __launch_bounds__(NT, 2) void gru_persistent(
    const float* __restrict__ x,
    const float* __restrict__ wih0, const float* __restrict__ whh0,
    const float* __restrict__ bih0, const float* __restrict__ bhh0,
    const float* __restrict__ wih1, const float* __restrict__ whh1,
    const float* __restrict__ bih1, const float* __restrict__ bhh1,
    const float* __restrict__ fcw, const float* __restrict__ fcb,
    u32* __restrict__ h0w,    // [3][B][H] tagged dwords
    u32* __restrict__ h1w,    // [3][B][H] tagged dwords
    float* __restrict__ out)
{
  __shared__ float lds[2 * LDSF];

  const int bid = blockIdx.x;
  const int g   = bid >> 5;
  const int wg  = bid & 31;
  const int tid = threadIdx.x;
  const int r0  = g * RPG;
  const int j0  = wg * 8;

  const int wave = tid >> 6, lane = tid & 63;
  const int lay  = wave >> 2;          // 0,1
  const int fam  = (wave >> 1) & 1;
  const int rh   = wave & 1;
  const int ju   = lane & 7;
  const int ks   = lane >> 3;
  const int jg   = j0 + ju;

  // zero partial buffers in BOTH parities (unwritten slots must stay 0)
  for (int i = tid; i < PBN; i += NT) {
    lds[O_PB + i] = 0.f;
    lds[LDSF + O_PB + i] = 0.f;
  }

  // ---- weight slices into registers (once) — r7 verbatim ----
  float4 wr0[8], wr1[8], wr2[8];
  if (lay == 0) {
    if (fam == 0) {
#define L0F0(wrg, gg) { \
      const float* wi = wih0 + (size_t)((gg) * kH + jg) * kI + ks * 8;   \
      const float* wh = whh0 + (size_t)((gg) * kH + jg) * kH + ks * 32;  \
      wrg[0] = F4(wi); wrg[1] = F4(wi + 4);                              \
      wrg[2] = F4(wh); wrg[3] = F4(wh + 4); wrg[4] = F4(wh + 8); }
      L0F0(wr0, 0) L0F0(wr1, 1) L0F0(wr2, 2)
    } else {
#define L0F1(wrg, gg) { \
      const float* wh = whh0 + (size_t)((gg) * kH + jg) * kH + ks * 32 + 12; \
      wrg[0] = F4(wh); wrg[1] = F4(wh + 4); wrg[2] = F4(wh + 8);             \
      wrg[3] = F4(wh + 12); wrg[4] = F4(wh + 16); }
      L0F1(wr0, 0) L0F1(wr1, 1) L0F1(wr2, 2)
    }
  } else {
    const float* ws = fam ? whh1 : wih1;
#define L1W(wrg, gg) { \
    const float* wp = ws + (size_t)((gg) * kH + jg) * kH + ks * 32;          \
    wrg[0] = F4(wp);      wrg[1] = F4(wp + 4);  wrg[2] = F4(wp + 8);         \
    wrg[3] = F4(wp + 12); wrg[4] = F4(wp + 16); wrg[5] = F4(wp + 20);        \
    wrg[6] = F4(wp + 24); wrg[7] = F4(wp + 28); }
    L1W(wr0, 0) L1W(wr1, 1) L1W(wr2, 2)
  }

  // ---- finisher constants (tid < 256: layf = tid>>7, uf = tid&7) ----
  float fb_r = 0.f, fb_z = 0.f, fn_i = 0.f, fn_h = 0.f;
  if (tid < 256) {
    const int layf = tid >> 7, uf = tid & 7, jf = j0 + uf;
    const float* bi = layf ? bih1 : bih0;
    const float* bh = layf ? bhh1 : bhh0;
    fb_r = bi[jf] + bh[jf];
    fb_z = bi[kH + jf] + bh[kH + jf];
    fn_i = bi[2 * kH + jf];
    fn_h = bh[2 * kH + jf];
  }

  // sweep element indices (4 u64 per buffer per thread)
  int RO[4], K2[4];
  #pragma unroll
  for (int p = 0; p < 4; ++p) {
    const int i = tid + p * NT;          // 0..2047
    RO[p] = i >> 7; K2[p] = i & 127;
  }

  // finish(u): gates + tagged publish, reading stage+partials from Lp
  auto finish_u = [&](int u, const float* Lp) {
    if (tid < 256) {
      const int layf = tid >> 7;
      const bool act = layf ? (u >= 1) : (u < kT);
      if (act) {
        const int rof = (tid >> 3) & 15, uf = tid & 7, jf = j0 + uf;
        const float* p0 = Lp + O_PB + ((layf * 2) * 16 + rof) * SRS + uf;
        const float* p1 = p0 + 16 * SRS;
        const float rr = sigf(p0[0] + p1[0] + fb_r);
        const float zz = sigf(p0[8] + p1[8] + fb_z);
        const float nn = tanhf(p0[16] + p1[16] + fn_i +
                               rr * (p0[24] + p1[24] + fn_h));
        const float hp = Lp[(layf ? O_S1 : O_S0) +
                            (jf >> 5) * SKS + rof * SRS + (jf & 31)];
        const float hv = (1.f - zz) * nn + zz * hp;
        const int slot = layf ? ((u - 1) % 3) : (u % 3);
        const u32 tag = layf ? (u32)(u & 3) : (u32)((u + 1) & 3);
        const u32 bits = (__float_as_uint(hv) & ~3u) | tag;
        u32* hw = (layf ? h1w : h0w) + (size_t)slot * kBH +
                  (size_t)(r0 + rof) * kH + jf;
        AS(hw, bits);
      }
    }
  };

  __syncthreads();

  // ---- 513 steps: 2 syncthreads each, no flags ----
  for (int s = 0; s <= kT; ++s) {
    float* Lc = lds + (s & 1) * LDSF;
    const float* Lp = lds + ((s & 1) ^ 1) * LDSF;

    const int slot0 = (s + 2) % 3;           // h0(s-1)
    const int slot1 = (s + 1) % 3;           // h1(s-2)
    const u32 e0 = (u32)(s & 3);
    const u32 e1 = (u32)((s - 1) & 3);

    // 1) pre-issue sweep + x loads (fly under finish)
    const ull* A0[4]; const ull* A1[4];
    ull v0[4], v1[4];
    #pragma unroll
    for (int p = 0; p < 4; ++p) {
      A0[p] = (const ull*)(h0w + (size_t)slot0 * kBH +
                           (size_t)(r0 + RO[p]) * kH) + K2[p];
      v0[p] = AL(A0[p]);
    }
    if (s >= 1) {
      #pragma unroll
      for (int p = 0; p < 4; ++p) {
        A1[p] = (const ull*)(h1w + (size_t)slot1 * kBH +
                             (size_t)(r0 + RO[p]) * kH) + K2[p];
        v1[p] = AL(A1[p]);
      }
    }
    float4 xv = {};
    if (s < kT && tid < 256) {
      const int ro = tid >> 4, c4 = (tid & 15) * 4;
      xv = F4(x + (size_t)(r0 + ro) * kT * kI + (size_t)s * kI + c4);
    }

    // 2) finish(s-1): gates + publish (overlaps the in-flight sweep)
    if (s >= 1) finish_u(s - 1, Lp);
    asm volatile("" ::: "memory");   // keep publish above the retry spin

    // 3) verify/retry sweep, unpack into Lc
    for (;;) {
      u32 bad = 0;
      #pragma unroll
      for (int p = 0; p < 4; ++p)
        bad |= ((u32)v0[p] ^ e0) | ((u32)(v0[p] >> 32) ^ e0);
      if (s >= 1) {
        #pragma unroll
        for (int p = 0; p < 4; ++p)
          bad |= ((u32)v1[p] ^ e1) | ((u32)(v1[p] >> 32) ^ e1);
      }
      if (!(bad & 3u)) break;
      __builtin_amdgcn_s_sleep(1);
      #pragma unroll
      for (int p = 0; p < 4; ++p) v0[p] = AL(A0[p]);
      if (s >= 1) {
        #pragma unroll
        for (int p = 0; p < 4; ++p) v1[p] = AL(A1[p]);
      }
    }
    #pragma unroll
    for (int p = 0; p < 4; ++p) {
      const int ksg = K2[p] >> 4, off = (K2[p] * 2) & 31, ro = RO[p];
      float2 f0; __builtin_memcpy(&f0, &v0[p], 8);
      *(float2*)(Lc + O_S0 + ksg * SKS + ro * SRS + off) = f0;
      if (s >= 1) {
        float2 f1; __builtin_memcpy(&f1, &v1[p], 8);
        *(float2*)(Lc + O_S1 + ksg * SKS + ro * SRS + off) = f1;
      }
    }
    if (s < kT && tid < 256) {
      const int ro = tid >> 4, c4 = (tid & 15) * 4;
      *(float4*)(Lc + O_X + ro * 68 + c4) = xv;
    }
    __syncthreads();

    // 4) dot phase (r7 verbatim, on Lc)
    const bool wact = lay ? (s >= 1) : (s < kT);
    if (wact) {
      float prr[8], pzz[8], pni[8], pnh[8];
      #pragma unroll
      for (int r = 0; r < 8; ++r) {
        const int ro = rh * 8 + r;
        float pr = 0.f, pz = 0.f, pxi = 0.f, pxh = 0.f;
        if (lay == 0) {
          if (fam == 0) {
            const float* ax = Lc + O_X + ro * 68 + ks * 8;
            const float4 x0 = F4(ax), x1 = F4(ax + 4);
            pr  += dot4(x0, wr0[0]) + dot4(x1, wr0[1]);
            pz  += dot4(x0, wr1[0]) + dot4(x1, wr1[1]);
            pxi += dot4(x0, wr2[0]) + dot4(x1, wr2[1]);
            const float* ah = Lc + O_S0 + ks * SKS + ro * SRS;
            #pragma unroll
            for (int i = 0; i < 3; ++i) {
              const float4 hv = F4(ah + i * 4);
              pr  += dot4(hv, wr0[2 + i]);
              pz  += dot4(hv, wr1[2 + i]);
              pxh += dot4(hv, wr2[2 + i]);
            }
          } else {
            const float* ah = Lc + O_S0 + ks * SKS + ro * SRS + 12;
            #pragma unroll
            for (int i = 0; i < 5; ++i) {
              const float4 hv = F4(ah + i * 4);
              pr  += dot4(hv, wr0[i]);
              pz  += dot4(hv, wr1[i]);
              pxh += dot4(hv, wr2[i]);
            }
          }
        } else {
          const float* aa = Lc + (fam ? O_S1 : O_S0) + ks * SKS + ro * SRS;
          #pragma unroll
          for (int i = 0; i < 8; ++i) {
            const float4 av = F4(aa + i * 4);
            pr += dot4(av, wr0[i]);
            pz += dot4(av, wr1[i]);
            if (fam) pxh += dot4(av, wr2[i]);
            else     pxi += dot4(av, wr2[i]);
          }
        }
        prr[r] = pr; pzz[r] = pz; pni[r] = pxi; pnh[r] = pxh;
      }
      #pragma unroll
      for (int r = 0; r < 8; ++r) { prr[r] = red8(prr[r]); pzz[r] = red8(pzz[r]); }
      if (lay == 0 && fam == 0) {
        #pragma unroll
        for (int r = 0; r < 8; ++r) { pni[r] = red8(pni[r]); pnh[r] = red8(pnh[r]); }
      } else if (fam == 0) {
        #pragma unroll
        for (int r = 0; r < 8; ++r) pni[r] = red8(pni[r]);
      } else {
        #pragma unroll
        for (int r = 0; r < 8; ++r) pnh[r] = red8(pnh[r]);
      }
      if (ks == 0) {
        #pragma unroll
        for (int r = 0; r < 8; ++r) {
          float* pb = Lc + O_PB + ((wave >> 1) * 16 + rh * 8 + r) * SRS + ju;
          pb[0] = prr[r]; pb[8] = pzz[r];
          if (lay == 0 && fam == 0) { pb[16] = pni[r]; pb[24] = pnh[r]; }
          else if (fam == 0)          pb[16] = pni[r];
          else                        pb[24] = pnh[r];
        }
      }
    }
    __syncthreads();
  }

  // ---- final finish(kT): publishes h1(kT-1) ----
  finish_u(kT, lds + (kT & 1) * LDSF);

  // ---- FC epilogue: group's WG0; h1(T-1) slot (kT-1)%3, tag kT&3 ----
  if (wg == 0 && tid < 256) {
    const int rv = tid >> 4, o = (tid >> 3) & 1, kseg = tid & 7;
    const u32* hf = h1w + (size_t)((kT - 1) % 3) * kBH + (size_t)(r0 + rv) * kH;
    const float* wfc = fcw + (size_t)o * kH;
    float acc = 0.f;
    for (int k = kseg * 32; k < kseg * 32 + 32; ++k) {
      u32 b;
      do {
        b = AL(hf + k);
      } while ((b & 3u) != (u32)(kT & 3));
      acc += fmaxf(__uint_as_float(b), 0.f) * wfc[k];
    }
    acc += __shfl_xor(acc, 1);
    acc += __shfl_xor(acc, 2);
    acc += __shfl_xor(acc, 4);
    if (kseg == 0) out[(r0 + rv) * 2 + o] = acc + fcb[o];
  }
}

extern "C" void kernel_launch(void* const* d_in, const int* in_sizes, int n_in,
                              void* d_out, int out_size, void* d_ws, size_t ws_size,
                              hipStream_t stream) {
  const float* x    = (const float*)d_in[0];
  const float* wih0 = (const float*)d_in[1];
  const float* whh0 = (const float*)d_in[2];
  const float* bih0 = (const float*)d_in[3];
  const float* bhh0 = (const float*)d_in[4];
  const float* wih1 = (const float*)d_in[5];
  const float* whh1 = (const float*)d_in[6];
  const float* bih1 = (const float*)d_in[7];
  const float* bhh1 = (const float*)d_in[8];
  const float* fcw  = (const float*)d_in[9];
  const float* fcb  = (const float*)d_in[10];

  u32* h0w = (u32*)d_ws;                 // [3][B][H] tagged
  u32* h1w = h0w + 3 * kBH;              // [3][B][H] tagged
  float* out = (float*)d_out;

  // zero tagged h buffers (tag 0 == t=-1 state) every call
  hipMemsetAsync(d_ws, 0, (size_t)(6 * kBH) * sizeof(u32), stream);

  gru_persistent<<<NWG, NT, 0, stream>>>(
      x, wih0, whh0, bih0, bhh0, wih1, whh1, bih1, bhh1,
      fcw, fcb, h0w, h1w, out);
}